// Round 1
// baseline (179.004 us; speedup 1.0000x reference)
//
#include <hip/hip_runtime.h>
#include <hip/hip_bf16.h>
#include <math.h>

#define B_ROWS 4096
#define D_DIM 512
#define TWO_B 8192
#define HW_N 256
#define BASE_T 0.07f
#define ALPHA_C 0.5f

typedef __bf16 v8bf __attribute__((ext_vector_type(8)));
typedef float v4f __attribute__((ext_vector_type(4)));

// ---------------------------------------------------------------------------
// Kernel 1: normalize, temps, pos_sim
// One block (256 thr) per sample row b.
// ---------------------------------------------------------------------------
__global__ __launch_bounds__(256) void prep_kernel(
    const float* __restrict__ emb1, const float* __restrict__ emb2,
    const float* __restrict__ att, __hip_bfloat16* __restrict__ X,
    float* __restrict__ inv_temp, float* __restrict__ pos)
{
    const int b = blockIdx.x;
    const int t = threadIdx.x;
    const float* e1 = emb1 + (size_t)b * D_DIM;
    const float* e2 = emb2 + (size_t)b * D_DIM;
    float a1 = e1[t], c1 = e1[t + 256];
    float a2 = e2[t], c2 = e2[t + 256];
    float av = att[(size_t)b * HW_N + t];
    float s1 = a1 * a1 + c1 * c1;
    float s2 = a2 * a2 + c2 * c2;
    float s12 = a1 * a2 + c1 * c2;
    #pragma unroll
    for (int m = 1; m < 64; m <<= 1) {
        s1  += __shfl_xor(s1, m, 64);
        s2  += __shfl_xor(s2, m, 64);
        s12 += __shfl_xor(s12, m, 64);
        av  += __shfl_xor(av, m, 64);
    }
    __shared__ float red[4][4];
    const int w = t >> 6, lane = t & 63;
    if (lane == 0) { red[w][0] = s1; red[w][1] = s2; red[w][2] = s12; red[w][3] = av; }
    __syncthreads();
    const float T1  = red[0][0] + red[1][0] + red[2][0] + red[3][0];
    const float T2  = red[0][1] + red[1][1] + red[2][1] + red[3][1];
    const float T12 = red[0][2] + red[1][2] + red[2][2] + red[3][2];
    const float Ta  = red[0][3] + red[1][3] + red[2][3] + red[3][3];
    const float n1 = fmaxf(sqrtf(T1), 1e-12f);
    const float n2 = fmaxf(sqrtf(T2), 1e-12f);
    const float i1 = 1.0f / n1, i2 = 1.0f / n2;
    const float it = 1.0f / (BASE_T * (1.0f + ALPHA_C * (Ta * (1.0f / 256.0f))));
    __hip_bfloat16* x1 = X + (size_t)b * D_DIM;
    __hip_bfloat16* x2 = X + (size_t)(b + B_ROWS) * D_DIM;
    x1[t]       = __float2bfloat16(a1 * i1);
    x1[t + 256] = __float2bfloat16(c1 * i1);
    x2[t]       = __float2bfloat16(a2 * i2);
    x2[t + 256] = __float2bfloat16(c2 * i2);
    if (t == 0) {
        inv_temp[b] = it;
        inv_temp[b + B_ROWS] = it;
        pos[b] = (T12 * i1 * i2) * it;   // pos_sim (same for rows b and B+b)
    }
}

// ---------------------------------------------------------------------------
// Kernel 2: Gram tiles + fused exp-row-sum.
// 128x128 tile per block, 4 waves in 2x2, each wave 64x64 via 4x4 MFMAs.
// ---------------------------------------------------------------------------
__device__ __forceinline__ void gload_lds16(const void* g, void* s) {
    __builtin_amdgcn_global_load_lds(
        (const __attribute__((address_space(1))) unsigned int*)g,
        (__attribute__((address_space(3))) unsigned int*)s,
        16, 0, 0);
}

__global__ __launch_bounds__(256) void gram_kernel(
    const __hip_bfloat16* __restrict__ X,
    const float* __restrict__ inv_temp,
    float* __restrict__ partial)
{
    __shared__ __hip_bfloat16 smA[128 * 32];
    __shared__ __hip_bfloat16 smB[128 * 32];

    const int cb = blockIdx.x;
    const int rb = blockIdx.y;
    const int rowBase = rb * 128;
    const int colBase = cb * 128;

    const int tid  = threadIdx.x;
    const int w    = tid >> 6;
    const int lane = tid & 63;
    const int quad = lane >> 4;
    const int t    = lane & 15;
    const int wm   = w >> 1;
    const int wn   = w & 1;

    // staging lane roles: 16 rows x 4 chunks(16B) per 64-lane call
    const int srow   = lane >> 2;
    const int schunk = lane & 3;

    v4f acc[4][4];
    #pragma unroll
    for (int a = 0; a < 4; a++)
        #pragma unroll
        for (int b2 = 0; b2 < 4; b2++)
            acc[a][b2] = v4f{0.0f, 0.0f, 0.0f, 0.0f};

    const __hip_bfloat16* Arow0 = X + (size_t)rowBase * D_DIM;
    const __hip_bfloat16* Brow0 = X + (size_t)colBase * D_DIM;

    for (int kk = 0; kk < D_DIM; kk += 32) {
        #pragma unroll
        for (int c = 0; c < 2; c++) {
            const int rg = w * 2 + c;             // 16-row group, wave-uniform
            const int r  = rg * 16 + srow;
            gload_lds16(Arow0 + (size_t)r * D_DIM + kk + schunk * 8, &smA[rg * 512]);
            gload_lds16(Brow0 + (size_t)r * D_DIM + kk + schunk * 8, &smB[rg * 512]);
        }
        __syncthreads();

        v8bf af[4], bf[4];
        #pragma unroll
        for (int mi = 0; mi < 4; mi++) {
            const int row = wm * 64 + mi * 16 + t;
            af[mi] = *(const v8bf*)&smA[row * 32 + quad * 8];
        }
        #pragma unroll
        for (int ni = 0; ni < 4; ni++) {
            const int col = wn * 64 + ni * 16 + t;
            bf[ni] = *(const v8bf*)&smB[col * 32 + quad * 8];
        }
        #pragma unroll
        for (int mi = 0; mi < 4; mi++)
            #pragma unroll
            for (int ni = 0; ni < 4; ni++)
                acc[mi][ni] = __builtin_amdgcn_mfma_f32_16x16x32_bf16(
                    af[mi], bf[ni], acc[mi][ni], 0, 0, 0);
        __syncthreads();
    }

    // Epilogue: exp + mask diag + row-sum, write partial slice (cb*2+wn)
    float* pslice = partial + (size_t)(cb * 2 + wn) * TWO_B;
    #pragma unroll
    for (int mi = 0; mi < 4; mi++) {
        #pragma unroll
        for (int r = 0; r < 4; r++) {
            const int i = rowBase + wm * 64 + mi * 16 + quad * 4 + r;
            const float it = inv_temp[i];
            float s = 0.0f;
            #pragma unroll
            for (int ni = 0; ni < 4; ni++) {
                const int j = colBase + wn * 64 + ni * 16 + t;
                const float v = acc[mi][ni][r] * it;
                s += (i == j) ? 0.0f : __expf(v);
            }
            s += __shfl_xor(s, 1, 64);
            s += __shfl_xor(s, 2, 64);
            s += __shfl_xor(s, 4, 64);
            s += __shfl_xor(s, 8, 64);
            if (t == 0) pslice[i] = s;
        }
    }
}

// ---------------------------------------------------------------------------
// Kernel 3a: denom = sum of 128 slices; loss_i = log(denom) - pos; block sums
// ---------------------------------------------------------------------------
__global__ __launch_bounds__(256) void finish1(
    const float* __restrict__ partial, const float* __restrict__ pos,
    float* __restrict__ blockSums)
{
    const int i = blockIdx.x * 256 + threadIdx.x;
    float d = 0.0f;
    for (int s = 0; s < 128; s++) d += partial[(size_t)s * TWO_B + i];
    float li = logf(d) - pos[i & (B_ROWS - 1)];
    #pragma unroll
    for (int m = 1; m < 64; m <<= 1) li += __shfl_xor(li, m, 64);
    __shared__ float red[4];
    const int w = threadIdx.x >> 6, lane = threadIdx.x & 63;
    if (lane == 0) red[w] = li;
    __syncthreads();
    if (threadIdx.x == 0) blockSums[blockIdx.x] = red[0] + red[1] + red[2] + red[3];
}

// ---------------------------------------------------------------------------
// Kernel 3b: final scalar
// ---------------------------------------------------------------------------
__global__ void finish2(const float* __restrict__ blockSums, float* __restrict__ out)
{
    const int lane = threadIdx.x;
    float v = (lane < 32) ? blockSums[lane] : 0.0f;
    #pragma unroll
    for (int m = 1; m < 64; m <<= 1) v += __shfl_xor(v, m, 64);
    if (lane == 0) out[0] = v * (1.0f / 8192.0f);
}

// ---------------------------------------------------------------------------
extern "C" void kernel_launch(void* const* d_in, const int* in_sizes, int n_in,
                              void* d_out, int out_size, void* d_ws, size_t ws_size,
                              hipStream_t stream) {
    const float* emb1 = (const float*)d_in[0];
    const float* emb2 = (const float*)d_in[1];
    const float* att  = (const float*)d_in[2];
    float* out = (float*)d_out;

    char* ws = (char*)d_ws;
    // layout: X bf16 [8192*512] = 8,388,608 B
    //         inv_temp f32 [8192] -> +32,768
    //         pos f32 [4096]      -> +16,384
    //         partial f32 [128*8192] -> +4,194,304
    //         blockSums f32 [32]  -> +128
    __hip_bfloat16* X  = (__hip_bfloat16*)ws;
    float* inv_temp    = (float*)(ws + 8388608);
    float* pos         = (float*)(ws + 8388608 + 32768);
    float* partial     = (float*)(ws + 8388608 + 32768 + 16384);
    float* blockSums   = (float*)(ws + 8388608 + 32768 + 16384 + 4194304);

    prep_kernel<<<B_ROWS, 256, 0, stream>>>(emb1, emb2, att, X, inv_temp, pos);
    dim3 g2(TWO_B / 128, TWO_B / 128);
    gram_kernel<<<g2, 256, 0, stream>>>(X, inv_temp, partial);
    finish1<<<TWO_B / 256, 256, 0, stream>>>(partial, pos, blockSums);
    finish2<<<1, 64, 0, stream>>>(blockSums, out);
}